// Round 10
// baseline (462.777 us; speedup 1.0000x reference)
//
#include <hip/hip_runtime.h>
#include <hip/hip_cooperative_groups.h>

namespace cg = cooperative_groups;

#define N_NODES 50000
#define N_EDGES 800000
#define IN_DIM 256
#define HID 64
#define OUT_DIM 16
#define GAT_IN 66   // HID + N_PROTO
#define HS_STRIDE 76   // LDS h-tile row stride (floats)
#define MEGA_ITERS 782 // 782*64 >= 50000 nodes (4 waves/blk-iter, 16 nodes/wave)
#define AGG_ITERS 12500
#define CAP 64         // esrc bucket capacity (deg mean 16, sd 4)

typedef unsigned short u16;
typedef unsigned int u32;
typedef __attribute__((ext_vector_type(8))) short s8v;
typedef __attribute__((ext_vector_type(4))) float f4v;
typedef __attribute__((ext_vector_type(2))) _Float16 h2;

__device__ __forceinline__ float bf2f(u16 u) {
  union { u32 i; float f; } v; v.i = ((u32)u) << 16; return v.f;
}
__device__ __forceinline__ u16 f2bf(float f) {
  union { float f; u32 i; } v; v.f = f;
  u32 r = v.i + 0x7FFFu + ((v.i >> 16) & 1u);
  return (u16)(r >> 16);
}
__device__ __forceinline__ u16 f2h(float f) {
  union { _Float16 h; u16 u; } v; v.h = (_Float16)f; return v.u;
}
__device__ __forceinline__ void split8(const float* uu, s8v& ah, s8v& al) {
  #pragma unroll
  for (int j = 0; j < 8; ++j) {
    u32 bits = __float_as_uint(uu[j]);
    u16 hb = (u16)(bits >> 16);
    ah[j] = (short)hb;
    al[j] = (short)f2bf(uu[j] - bf2f(hb));
  }
}
__device__ __forceinline__ int probe_i64(const void* ei) {
  const long long* e64 = (const long long*)ei;
  int ok = 1;
  #pragma unroll
  for (int k = 0; k < 16; k++) {
    long long v = e64[k];
    if (v < 0 || v >= N_NODES) { ok = 0; break; }
  }
  return ok;
}

template <int CTRL>
__device__ __forceinline__ float dppadd(float g) {
  return g + __int_as_float(__builtin_amdgcn_update_dpp(
      0, __float_as_int(g), CTRL, 0xF, 0xF, true));
}
__device__ __forceinline__ float red16_dpp(float g) {
  g = dppadd<0xB1>(g);   // quad_perm [1,0,3,2]
  g = dppadd<0x4E>(g);   // quad_perm [2,3,0,1]
  g = dppadd<0x124>(g);  // row_ror:4
  g = dppadd<0x128>(g);  // row_ror:8
  return g;
}
__device__ __forceinline__ float edge_h(uint2 rv, h2 xr01, h2 xr23,
                                        h2 av01, h2 av23,
                                        h2& x01, h2& x23) {
  x01 = __builtin_bit_cast(h2, rv.x);
  x23 = __builtin_bit_cast(h2, rv.y);
  h2 t01 = x01 + xr01, t23 = x23 + xr23;
  t01 = __builtin_elementwise_max(t01, t01 * (_Float16)0.2f);
  t23 = __builtin_elementwise_max(t23, t23 * (_Float16)0.2f);
  float g = __builtin_amdgcn_fdot2(t01, av01, 0.f, false);
  return __builtin_amdgcn_fdot2(t23, av23, g, false);
}

// ---------------------------------------------------------------------------
// K_ALL<FULL>: whole pipeline in ONE cooperative kernel.
//   P1 prep: weights -> MFMA B-fragment tables; zero cnt; edge-dtype probe.
//   grid.sync()
//   P2: blocks [0,Gm) mega (grid-stride over 782 tile-groups, R14 body);
//       blocks [Gm,G) scatter edges into fixed-capacity buckets.
//   grid.sync()
//   P3 agg: grid-stride over 12500 node-groups (R16 body, bucket CSR).
// No early returns before the final phase (guards only) -> grid barrier safe.
// FULL=1: xls+xrs; FULL=0: xls+ha, agg recomputes xr from ha via LDS weights.
// ---------------------------------------------------------------------------
template <int FULL>
__global__ __launch_bounds__(256) void k_all(
    const float* __restrict__ x, const void* __restrict__ ei,
    const float* __restrict__ Win, const float* __restrict__ bin,
    const float* __restrict__ proto,
    const float* __restrict__ Wl, const float* __restrict__ bl,
    const float* __restrict__ Wr, const float* __restrict__ br,
    const float* __restrict__ att, const float* __restrict__ gbias,
    const float* __restrict__ wcls, const float* __restrict__ bcls,
    u16* __restrict__ wbT, u16* __restrict__ wlT, u16* __restrict__ wrT,
    int* __restrict__ cnt, int* __restrict__ flags, int* __restrict__ esrc_b,
    float* __restrict__ ha, u16* __restrict__ xls, u16* __restrict__ xrs,
    float* __restrict__ out)
{
  cg::grid_group grid = cg::this_grid();
  const int G = gridDim.x;
  const int gid = blockIdx.x * 256 + threadIdx.x;
  const int gstride = G * 256;
  const int lane = threadIdx.x & 63;
  const int wv = threadIdx.x >> 6;

  // LDS union: P2 hs-tiles (19456B) / P3 fallback weight cache (33792B)
  constexpr int HS_BYTES = 4 * 16 * HS_STRIDE * 4;
  constexpr int WR_BYTES = GAT_IN * 256 * 2;
  constexpr int SMEM = FULL ? HS_BYTES : (WR_BYTES > HS_BYTES ? WR_BYTES : HS_BYTES);
  __shared__ __align__(16) char smem[SMEM];

  // ======================= P1: prep =======================
  for (int i = gid; i < N_NODES; i += gstride) cnt[i] = 0;
  if (gid == 0) flags[1] = probe_i64(ei);
  for (int m = gid; m < 16384; m += gstride) {
    int s = m >> 11, rem = m & 2047;
    int t = rem >> 9, rem2 = rem & 511;
    int l = rem2 >> 3, j = rem2 & 7;
    int k = s * 32 + (l >> 4) * 8 + j;
    int c = t * 16 + (l & 15);
    wbT[m] = f2bf(Win[k * 64 + c]);
  }
  for (int m = gid; m < 24576; m += gstride) {
    int s = m >> 13, rem = m & 8191;
    int t = rem >> 9, rem2 = rem & 511;
    int l = rem2 >> 3, j = rem2 & 7;
    int k = s * 32 + (l >> 4) * 8 + j;
    int j2 = t * 16 + (l & 15);
    u16 vl = 0, vr = 0;
    if (k < GAT_IN) {
      vl = f2bf(Wl[k * 256 + j2]);
      vr = f2bf(Wr[k * 256 + j2]);
    }
    wlT[m] = vl;
    wrT[m] = vr;
  }
  grid.sync();

  // ======================= P2: mega || scatter =======================
  int Gm = (G * 4) / 5;
  if (Gm > MEGA_ITERS) Gm = MEGA_ITERS;
  if (Gm < 1) Gm = 1;
  if (Gm >= G) Gm = G - 1;

  if (blockIdx.x < Gm) {
    float* hs = (float*)smem + wv * (16 * HS_STRIDE);
    for (int b = blockIdx.x; b < MEGA_ITERS; b += Gm) {
      const int nb = b * 64 + wv * 16;
      if (nb < N_NODES) {
        const int mrow = lane & 15, q = lane >> 4;
        // ---- h = relu(x @ Win + bin); sem = cosine sims ----
        f4v acc0 = {0.f,0.f,0.f,0.f}, acc1 = {0.f,0.f,0.f,0.f};
        f4v acc2 = {0.f,0.f,0.f,0.f}, acc3 = {0.f,0.f,0.f,0.f};
        const float* xrow = x + (size_t)(nb + mrow) * IN_DIM + q * 8;
        #pragma unroll 4
        for (int s = 0; s < 8; ++s) {
          float4 u0 = *(const float4*)(xrow + s * 32);
          float4 u1 = *(const float4*)(xrow + s * 32 + 4);
          float uu[8] = {u0.x, u0.y, u0.z, u0.w, u1.x, u1.y, u1.z, u1.w};
          s8v ah, al;
          split8(uu, ah, al);
          const u16* wp = wbT + s * 2048 + lane * 8;
          s8v b0 = *(const s8v*)(wp);
          s8v b1 = *(const s8v*)(wp + 512);
          s8v b2 = *(const s8v*)(wp + 1024);
          s8v b3 = *(const s8v*)(wp + 1536);
          acc0 = __builtin_amdgcn_mfma_f32_16x16x32_bf16(ah, b0, acc0, 0, 0, 0);
          acc0 = __builtin_amdgcn_mfma_f32_16x16x32_bf16(al, b0, acc0, 0, 0, 0);
          acc1 = __builtin_amdgcn_mfma_f32_16x16x32_bf16(ah, b1, acc1, 0, 0, 0);
          acc1 = __builtin_amdgcn_mfma_f32_16x16x32_bf16(al, b1, acc1, 0, 0, 0);
          acc2 = __builtin_amdgcn_mfma_f32_16x16x32_bf16(ah, b2, acc2, 0, 0, 0);
          acc2 = __builtin_amdgcn_mfma_f32_16x16x32_bf16(al, b2, acc2, 0, 0, 0);
          acc3 = __builtin_amdgcn_mfma_f32_16x16x32_bf16(ah, b3, acc3, 0, 0, 0);
          acc3 = __builtin_amdgcn_mfma_f32_16x16x32_bf16(al, b3, acc3, 0, 0, 0);
        }

        float bt[4], p0t[4], p1t[4];
        #pragma unroll
        for (int t = 0; t < 4; ++t) {
          bt[t]  = bin[t * 16 + mrow];
          p0t[t] = proto[t * 16 + mrow];
          p1t[t] = proto[64 + t * 16 + mrow];
        }
        float np0 = 0.f, np1 = 0.f;
        #pragma unroll
        for (int t = 0; t < 4; ++t) { np0 += p0t[t] * p0t[t]; np1 += p1t[t] * p1t[t]; }
        #pragma unroll
        for (int mm = 1; mm < 16; mm <<= 1) {
          np0 += __shfl_xor(np0, mm); np1 += __shfl_xor(np1, mm);
        }
        const float ip0 = 1.f / (sqrtf(np0) + 1e-12f);
        const float ip1 = 1.f / (sqrtf(np1) + 1e-12f);

        float hcol[4][4];
        #pragma unroll
        for (int r = 0; r < 4; ++r) {
          hcol[0][r] = fmaxf(acc0[r] + bt[0], 0.f);
          hcol[1][r] = fmaxf(acc1[r] + bt[1], 0.f);
          hcol[2][r] = fmaxf(acc2[r] + bt[2], 0.f);
          hcol[3][r] = fmaxf(acc3[r] + bt[3], 0.f);
        }
        #pragma unroll
        for (int r = 0; r < 4; ++r) {
          float r0 = 0.f, r1 = 0.f, r2 = 0.f;
          #pragma unroll
          for (int t = 0; t < 4; ++t) {
            float h = hcol[t][r];
            r0 += h * h; r1 += h * p0t[t]; r2 += h * p1t[t];
          }
          #pragma unroll
          for (int mm = 1; mm < 16; mm <<= 1) {
            r0 += __shfl_xor(r0, mm); r1 += __shfl_xor(r1, mm); r2 += __shfl_xor(r2, mm);
          }
          const int node = q * 4 + r;
          #pragma unroll
          for (int t = 0; t < 4; ++t)
            hs[node * HS_STRIDE + t * 16 + mrow] = hcol[t][r];
          if (!FULL) {
            float* row = ha + (size_t)(nb + node) * 68;
            #pragma unroll
            for (int t = 0; t < 4; ++t) row[t * 16 + mrow] = hcol[t][r];
          }
          if (mrow == 0) {
            float hi = 1.f / (sqrtf(r0) + 1e-12f);
            float s0 = r1 * hi * ip0, s1 = r2 * hi * ip1;
            hs[node * HS_STRIDE + 64] = s0;
            hs[node * HS_STRIDE + 65] = s1;
            if (!FULL) {
              float* row = ha + (size_t)(nb + node) * 68;
              row[64] = s0; row[65] = s1;
            }
          }
        }

        // ---- A-fragments from LDS h-tile ----
        s8v ahs[3], als[3];
        #pragma unroll
        for (int s = 0; s < 3; ++s) {
          float uu[8];
          if (s < 2) {
            float4 u0 = *(const float4*)(hs + mrow * HS_STRIDE + s * 32 + q * 8);
            float4 u1 = *(const float4*)(hs + mrow * HS_STRIDE + s * 32 + q * 8 + 4);
            uu[0]=u0.x; uu[1]=u0.y; uu[2]=u0.z; uu[3]=u0.w;
            uu[4]=u1.x; uu[5]=u1.y; uu[6]=u1.z; uu[7]=u1.w;
          } else {
            #pragma unroll
            for (int j = 0; j < 8; ++j) uu[j] = 0.f;
            if (q == 0) {
              uu[0] = hs[mrow * HS_STRIDE + 64];
              uu[1] = hs[mrow * HS_STRIDE + 65];
            }
          }
          split8(uu, ahs[s], als[s]);
        }

        // ---- merged xl (and xr when FULL) t-loop ----
        #pragma unroll 2
        for (int t = 0; t < 16; ++t) {
          f4v accl = {0.f, 0.f, 0.f, 0.f};
          f4v accr = {0.f, 0.f, 0.f, 0.f};
          #pragma unroll
          for (int s = 0; s < 3; ++s) {
            s8v bvl = *(const s8v*)(wlT + s * 8192 + t * 512 + lane * 8);
            accl = __builtin_amdgcn_mfma_f32_16x16x32_bf16(ahs[s], bvl, accl, 0, 0, 0);
            accl = __builtin_amdgcn_mfma_f32_16x16x32_bf16(als[s], bvl, accl, 0, 0, 0);
          }
          if (FULL) {
            #pragma unroll
            for (int s = 0; s < 3; ++s) {
              s8v bvr = *(const s8v*)(wrT + s * 8192 + t * 512 + lane * 8);
              accr = __builtin_amdgcn_mfma_f32_16x16x32_bf16(ahs[s], bvr, accr, 0, 0, 0);
              accr = __builtin_amdgcn_mfma_f32_16x16x32_bf16(als[s], bvr, accr, 0, 0, 0);
            }
          }
          float bcl = bl[t * 16 + mrow];
          #pragma unroll
          for (int r = 0; r < 4; ++r)
            xls[(size_t)(nb + q * 4 + r) * 256 + t * 16 + mrow] = f2h(accl[r] + bcl);
          if (FULL) {
            float bcr = br[t * 16 + mrow];
            #pragma unroll
            for (int r = 0; r < 4; ++r)
              xrs[(size_t)(nb + q * 4 + r) * 256 + t * 16 + mrow] = f2h(accr[r] + bcr);
          }
        }
      }  // nb guard
    }    // mega grid-stride
  } else {
    // ---- scatter role ----
    const int isl = flags[1];
    const int t0 = (blockIdx.x - Gm) * 256 + threadIdx.x;
    const int sstr = (G - Gm) * 256;
    if (isl) {
      const long long* es = (const long long*)ei;
      for (int e = t0; e < N_EDGES; e += sstr) {
        int s = (int)es[e], d = (int)es[N_EDGES + e];
        if ((unsigned)d >= N_NODES) continue;
        if ((unsigned)s >= N_NODES) s = 0;
        int p = atomicAdd(&cnt[d], 1);
        if (p < CAP) esrc_b[((size_t)d << 6) + p] = s;
      }
    } else {
      const int* es = (const int*)ei;
      for (int e = t0; e < N_EDGES; e += sstr) {
        int s = es[e], d = es[N_EDGES + e];
        if ((unsigned)d >= N_NODES) continue;
        if ((unsigned)s >= N_NODES) s = 0;
        int p = atomicAdd(&cnt[d], 1);
        if (p < CAP) esrc_b[((size_t)d << 6) + p] = s;
      }
    }
  }
  grid.sync();

  // ======================= P3: agg =======================
  u16* wr = (u16*)smem;
  if (!FULL) {
    for (int m = threadIdx.x; m < GAT_IN * 256; m += 256) wr[m] = f2bf(Wr[m]);
    __syncthreads();
  }
  float4 avr = *(const float4*)(att + lane * 4);
  const h2 av01 = {(_Float16)avr.x, (_Float16)avr.y};
  const h2 av23 = {(_Float16)avr.z, (_Float16)avr.w};
  const char* __restrict__ xbp = (const char*)xls;
  const u32 loff = (u32)lane * 8u;
  #define GROW(s) (*(const uint2*)(xbp + ((((u32)(s)) << 9) + loff)))

  for (int blk = blockIdx.x; blk < AGG_ITERS; blk += G) {
    const int n = __builtin_amdgcn_readfirstlane(blk * 4 + wv);
    if (n >= N_NODES) continue;

    h2 xr01, xr23;
    if (!FULL) {
      float4 bv = *(const float4*)(br + lane * 4);
      float y0 = bv.x, y1 = bv.y, y2 = bv.z, y3 = bv.w;
      const float* hrow = ha + (size_t)n * 68;
      for (int i = 0; i < GAT_IN; ++i) {
        ushort4 wvv = *(const ushort4*)&wr[i * 256 + lane * 4];
        float hv = hrow[i];
        y0 += hv * bf2f(wvv.x); y1 += hv * bf2f(wvv.y);
        y2 += hv * bf2f(wvv.z); y3 += hv * bf2f(wvv.w);
      }
      xr01 = (h2){(_Float16)y0, (_Float16)y1};
      xr23 = (h2){(_Float16)y2, (_Float16)y3};
    } else {
      uint2 qv = *(const uint2*)(xrs + (size_t)n * 256 + lane * 4);
      xr01 = __builtin_bit_cast(h2, qv.x);
      xr23 = __builtin_bit_cast(h2, qv.y);
    }

    const int kb = n << 6;
    int dg = __builtin_amdgcn_readfirstlane(cnt[n]);
    if (dg < 0) dg = 0;
    if (dg > CAP) dg = CAP;
    const int ke = kb + dg;
    const int nq = dg >> 2;

    uint2 p0, p1, p2, p3;
    uint2 n0, n1, n2, n3;
    int j0 = 0, j1 = 0, j2 = 0, j3 = 0;
    if (nq > 0) {
      int a0 = esrc_b[kb], a1 = esrc_b[kb + 1], a2 = esrc_b[kb + 2], a3 = esrc_b[kb + 3];
      p0 = GROW(a0); p1 = GROW(a1); p2 = GROW(a2); p3 = GROW(a3);
      if (nq > 1) {
        int b0 = esrc_b[kb + 4], b1 = esrc_b[kb + 5], b2 = esrc_b[kb + 6], b3 = esrc_b[kb + 7];
        n0 = GROW(b0); n1 = GROW(b1); n2 = GROW(b2); n3 = GROW(b3);
        if (nq > 2) {
          j0 = esrc_b[kb + 8];  j1 = esrc_b[kb + 9];
          j2 = esrc_b[kb + 10]; j3 = esrc_b[kb + 11];
        }
      }
    }

    float l_, c0, c1, c2, c3;
    {
      uint2 rv = GROW(n);
      h2 x01, x23;
      float g = edge_h(rv, xr01, xr23, av01, av23, x01, x23);
      g = red16_dpp(g);
      float a = __expf(fminf(g, 60.f));
      l_ = a;
      c0 = a * (float)x01[0]; c1 = a * (float)x01[1];
      c2 = a * (float)x23[0]; c3 = a * (float)x23[1];
    }

    for (int q = 0; q < nq; ++q) {
      uint2 r0 = p0, r1 = p1, r2 = p2, r3 = p3;
      p0 = n0; p1 = n1; p2 = n2; p3 = n3;
      if (q + 2 < nq) {
        n0 = GROW(j0); n1 = GROW(j1); n2 = GROW(j2); n3 = GROW(j3);
        if (q + 3 < nq) {
          int ib = kb + (q + 3) * 4;
          j0 = esrc_b[ib];     j1 = esrc_b[ib + 1];
          j2 = esrc_b[ib + 2]; j3 = esrc_b[ib + 3];
        }
      }
      h2 xa01, xa23, xb01, xb23, xc01, xc23, xd01, xd23;
      float g0 = edge_h(r0, xr01, xr23, av01, av23, xa01, xa23);
      float g1 = edge_h(r1, xr01, xr23, av01, av23, xb01, xb23);
      float g2 = edge_h(r2, xr01, xr23, av01, av23, xc01, xc23);
      float g3 = edge_h(r3, xr01, xr23, av01, av23, xd01, xd23);
      g0 = red16_dpp(g0); g1 = red16_dpp(g1);
      g2 = red16_dpp(g2); g3 = red16_dpp(g3);
      float a0 = __expf(fminf(g0, 60.f));
      float a1 = __expf(fminf(g1, 60.f));
      float a2 = __expf(fminf(g2, 60.f));
      float a3 = __expf(fminf(g3, 60.f));
      l_ += (a0 + a1) + (a2 + a3);
      c0 += a0 * (float)xa01[0] + a1 * (float)xb01[0]
          + a2 * (float)xc01[0] + a3 * (float)xd01[0];
      c1 += a0 * (float)xa01[1] + a1 * (float)xb01[1]
          + a2 * (float)xc01[1] + a3 * (float)xd01[1];
      c2 += a0 * (float)xa23[0] + a1 * (float)xb23[0]
          + a2 * (float)xc23[0] + a3 * (float)xd23[0];
      c3 += a0 * (float)xa23[1] + a1 * (float)xb23[1]
          + a2 * (float)xc23[1] + a3 * (float)xd23[1];
    }

    for (int i = kb + nq * 4; i < ke; ++i) {
      int s = esrc_b[i];
      uint2 rv = GROW(s);
      h2 x01, x23;
      float g = edge_h(rv, xr01, xr23, av01, av23, x01, x23);
      g = red16_dpp(g);
      float a = __expf(fminf(g, 60.f));
      l_ += a;
      c0 += a * (float)x01[0]; c1 += a * (float)x01[1];
      c2 += a * (float)x23[0]; c3 += a * (float)x23[1];
    }

    float inv = 1.f / (l_ + 1e-16f);
    float v0 = c0 * inv, v1 = c1 * inv, v2 = c2 * inv, v3 = c3 * inv;
    v0 += __shfl_xor(v0, 16); v0 += __shfl_xor(v0, 32);
    v1 += __shfl_xor(v1, 16); v1 += __shfl_xor(v1, 32);
    v2 += __shfl_xor(v2, 16); v2 += __shfl_xor(v2, 32);
    v3 += __shfl_xor(v3, 16); v3 += __shfl_xor(v3, 32);
    const int g4 = (lane & 15) * 4;
    const int h = lane >> 4;
    float4 gb = *(const float4*)(gbias + g4);
    v0 = fmaxf(0.25f * v0 + gb.x, 0.f);
    v1 = fmaxf(0.25f * v1 + gb.y, 0.f);
    v2 = fmaxf(0.25f * v2 + gb.z, 0.f);
    v3 = fmaxf(0.25f * v3 + gb.w, 0.f);
    float4 w0 = *(const float4*)(wcls + (g4 + 0) * 16 + h * 4);
    float4 w1 = *(const float4*)(wcls + (g4 + 1) * 16 + h * 4);
    float4 w2 = *(const float4*)(wcls + (g4 + 2) * 16 + h * 4);
    float4 w3 = *(const float4*)(wcls + (g4 + 3) * 16 + h * 4);
    float o0 = v0 * w0.x + v1 * w1.x + v2 * w2.x + v3 * w3.x;
    float o1 = v0 * w0.y + v1 * w1.y + v2 * w2.y + v3 * w3.y;
    float o2 = v0 * w0.z + v1 * w1.z + v2 * w2.z + v3 * w3.z;
    float o3 = v0 * w0.w + v1 * w1.w + v2 * w2.w + v3 * w3.w;
    #pragma unroll
    for (int mm = 1; mm < 16; mm <<= 1) {
      o0 += __shfl_xor(o0, mm); o1 += __shfl_xor(o1, mm);
      o2 += __shfl_xor(o2, mm); o3 += __shfl_xor(o3, mm);
    }
    if ((lane & 15) == 0) {
      float4 bcv = *(const float4*)(bcls + h * 4);
      float4 ov;
      ov.x = o0 + bcv.x; ov.y = o1 + bcv.y; ov.z = o2 + bcv.z; ov.w = o3 + bcv.w;
      *(float4*)(out + (size_t)n * 16 + h * 4) = ov;
    }
  }
  #undef GROW
}

// ---------------------------------------------------------------------------
extern "C" void kernel_launch(void* const* d_in, const int* in_sizes, int n_in,
                              void* d_out, int out_size, void* d_ws, size_t ws_size,
                              hipStream_t stream)
{
  const float* x     = (const float*)d_in[0];
  const void*  ei    = d_in[1];
  const float* Win   = (const float*)d_in[2];
  const float* bin   = (const float*)d_in[3];
  const float* proto = (const float*)d_in[4];
  const float* Wl    = (const float*)d_in[5];
  const float* bl    = (const float*)d_in[6];
  const float* Wr    = (const float*)d_in[7];
  const float* br    = (const float*)d_in[8];
  const float* att   = (const float*)d_in[9];
  const float* gbias = (const float*)d_in[10];
  const float* wcls  = (const float*)d_in[11];
  const float* bcls  = (const float*)d_in[12];
  float* out = (float*)d_out;

  char* p = (char*)d_ws;
  size_t used = 0;
  auto carve = [&](size_t bytes) {
    char* q = p + used;
    used += (bytes + 255) & ~(size_t)255;
    return (void*)q;
  };
  int* flags  = (int*)carve(256);
  int* cnt    = (int*)carve(N_NODES * 4);
  int* esrc_b = (int*)carve((size_t)N_NODES * CAP * 4);
  u16* wbT    = (u16*)carve(16384 * 2);
  u16* wlT    = (u16*)carve(24576 * 2);
  u16* wrT    = (u16*)carve(24576 * 2);
  u16* xls    = (u16*)carve((size_t)N_NODES * 256 * 2);
  const size_t base = used;
  void* big = carve((size_t)N_NODES * 256 * 2);  // 25.6 MB (ha or xrs)
  float* ha = (float*)big;
  u16* xrs  = (u16*)big;
  const bool full = ws_size >= base + (size_t)N_NODES * 256 * 2;

  // Cooperative grid sizing (host queries; cached; graph-capture safe).
  static int grid_full = 0, grid_fb = 0, num_cu = 0;
  if (num_cu == 0) {
    hipDeviceProp_t prop;
    int dev = 0;
    if (hipGetDevice(&dev) != hipSuccess) dev = 0;
    if (hipGetDeviceProperties(&prop, dev) == hipSuccess)
      num_cu = prop.multiProcessorCount;
    else
      num_cu = 256;
  }
  void* args[] = {
    (void*)&x, (void*)&ei, (void*)&Win, (void*)&bin, (void*)&proto,
    (void*)&Wl, (void*)&bl, (void*)&Wr, (void*)&br,
    (void*)&att, (void*)&gbias, (void*)&wcls, (void*)&bcls,
    (void*)&wbT, (void*)&wlT, (void*)&wrT,
    (void*)&cnt, (void*)&flags, (void*)&esrc_b,
    (void*)&ha, (void*)&xls, (void*)&xrs, (void*)&out
  };
  if (full) {
    if (grid_full == 0) {
      int mb = 0;
      if (hipOccupancyMaxActiveBlocksPerMultiprocessor(&mb, k_all<1>, 256, 0)
              != hipSuccess || mb < 1)
        mb = 4;
      long g = (long)mb * num_cu;
      if (g > 2048) g = 2048;
      if (g < 2) g = 2;
      grid_full = (int)g;
    }
    hipLaunchCooperativeKernel(k_all<1>, dim3(grid_full), dim3(256),
                               args, 0, stream);
  } else {
    if (grid_fb == 0) {
      int mb = 0;
      if (hipOccupancyMaxActiveBlocksPerMultiprocessor(&mb, k_all<0>, 256, 0)
              != hipSuccess || mb < 1)
        mb = 2;
      long g = (long)mb * num_cu;
      if (g > 2048) g = 2048;
      if (g < 2) g = 2;
      grid_fb = (int)g;
    }
    hipLaunchCooperativeKernel(k_all<0>, dim3(grid_fb), dim3(256),
                               args, 0, stream);
  }
}

// Round 11
// 222.311 us; speedup vs baseline: 2.0817x; 2.0817x over previous
//
#include <hip/hip_runtime.h>

#define N_NODES 50000
#define N_EDGES 800000
#define IN_DIM 256
#define HID 64
#define OUT_DIM 16
#define GAT_IN 66   // HID + N_PROTO
#define HS_STRIDE 76  // LDS h-tile row stride (floats): 4-aligned, bank-spread
#define MEGA_BLOCKS 782        // 782*64 >= 50000 nodes (4 waves/block, 16 nodes/wave)
#define SCAT_BLOCKS 3125       // 3125*256 = 800000 edges
#define CAP 64                 // esrc bucket capacity per node (deg mean 16, sd 4)

typedef unsigned short u16;
typedef unsigned int u32;
typedef __attribute__((ext_vector_type(8))) short s8v;    // 8 bf16 (4 VGPRs)
typedef __attribute__((ext_vector_type(4))) float f4v;    // MFMA accumulator
typedef __attribute__((ext_vector_type(2))) _Float16 h2;  // packed f16 pair

__device__ __forceinline__ float bf2f(u16 u) {
  union { u32 i; float f; } v; v.i = ((u32)u) << 16; return v.f;
}
__device__ __forceinline__ u16 f2bf(float f) {
  union { float f; u32 i; } v; v.f = f;
  u32 r = v.i + 0x7FFFu + ((v.i >> 16) & 1u);
  return (u16)(r >> 16);
}
__device__ __forceinline__ u16 f2h(float f) {
  union { _Float16 h; u16 u; } v; v.h = (_Float16)f; return v.u;
}
__device__ __forceinline__ void split8(const float* uu, s8v& ah, s8v& al) {
  #pragma unroll
  for (int j = 0; j < 8; ++j) {
    u32 bits = __float_as_uint(uu[j]);
    u16 hb = (u16)(bits >> 16);
    ah[j] = (short)hb;
    al[j] = (short)f2bf(uu[j] - bf2f(hb));
  }
}

// --------------------------- edge-dtype probe ------------------------------
__device__ __forceinline__ int probe_i64(const void* ei) {
  const long long* e64 = (const long long*)ei;
  int ok = 1;
  #pragma unroll
  for (int k = 0; k < 16; k++) {
    long long v = e64[k];
    if (v < 0 || v >= N_NODES) { ok = 0; break; }
  }
  return ok;
}

// ---------------------------------------------------------------------------
// K_PREP: weights -> MFMA B-fragment order; zero cnt (200 KB); edge-dtype
// probe computed once (flags[1]).
// ---------------------------------------------------------------------------
__global__ __launch_bounds__(256) void k_prep(
    const float* __restrict__ Win, const float* __restrict__ Wl,
    const float* __restrict__ Wr, const void* __restrict__ ei,
    u16* __restrict__ wbT, u16* __restrict__ wlT, u16* __restrict__ wrT,
    int* __restrict__ cnt, int* __restrict__ flags)
{
  const int gid = blockIdx.x * 256 + threadIdx.x;
  const int stride = gridDim.x * 256;
  for (int i = gid; i < N_NODES; i += stride) cnt[i] = 0;
  if (gid == 0) { flags[0] = 0; flags[1] = probe_i64(ei); }
  for (int m = gid; m < 16384; m += stride) {
    int s = m >> 11, rem = m & 2047;
    int t = rem >> 9, rem2 = rem & 511;
    int l = rem2 >> 3, j = rem2 & 7;
    int k = s * 32 + (l >> 4) * 8 + j;
    int c = t * 16 + (l & 15);
    wbT[m] = f2bf(Win[k * 64 + c]);
  }
  for (int m = gid; m < 24576; m += stride) {
    int s = m >> 13, rem = m & 8191;
    int t = rem >> 9, rem2 = rem & 511;
    int l = rem2 >> 3, j = rem2 & 7;
    int k = s * 32 + (l >> 4) * 8 + j;
    int j2 = t * 16 + (l & 15);
    u16 vl = 0, vr = 0;
    if (k < GAT_IN) {
      vl = f2bf(Wl[k * 256 + j2]);
      vr = f2bf(Wr[k * 256 + j2]);
    }
    wlT[m] = vl;
    wrT[m] = vr;
  }
}

// ---------------------------------------------------------------------------
// K_WORK<FULL>: block-role fusion (R19, best measured). Blocks [0,MEGA_BLOCKS)
// run the mega body; blocks [MEGA_BLOCKS, MEGA_BLOCKS+SCAT_BLOCKS) scatter
// edges into fixed-capacity buckets. Scatter's returning atomics hide under
// mega's MFMA work (different waves -> no vmcnt coupling).
// ---------------------------------------------------------------------------
template <int FULL>
__global__ __launch_bounds__(256) void k_work(
    const float* __restrict__ x,
    const u16* __restrict__ wbT, const float* __restrict__ bin,
    const float* __restrict__ proto,
    const u16* __restrict__ wlT, const float* __restrict__ bl,
    const u16* __restrict__ wrT, const float* __restrict__ br,
    float* __restrict__ ha, u16* __restrict__ xls, u16* __restrict__ xrs,
    const void* __restrict__ ei, const int* __restrict__ flags,
    int* __restrict__ cnt, int* __restrict__ esrc_b)
{
  if (blockIdx.x >= MEGA_BLOCKS) {
    // ---- scatter role: one edge per thread ----
    const int e = (blockIdx.x - MEGA_BLOCKS) * 256 + threadIdx.x;
    if (e >= N_EDGES) return;
    const int isl = flags[1];
    int s, d;
    if (isl) {
      s = (int)((const long long*)ei)[e];
      d = (int)((const long long*)ei)[N_EDGES + e];
    } else {
      s = ((const int*)ei)[e];
      d = ((const int*)ei)[N_EDGES + e];
    }
    if ((unsigned)d >= N_NODES) return;
    if ((unsigned)s >= N_NODES) s = 0;
    int p = atomicAdd(&cnt[d], 1);
    if (p < CAP) esrc_b[((size_t)d << 6) + p] = s;
    return;
  }

  // ---- mega role (R14 unsplit body) ----
  const int lane = threadIdx.x & 63;
  const int wv = threadIdx.x >> 6;
  const int nb = blockIdx.x * 64 + wv * 16;
  if (nb >= N_NODES) return;
  const int mrow = lane & 15, q = lane >> 4;

  __shared__ float hs_all[4][16 * HS_STRIDE];  // 19.5 KB, per-wave private
  float* hs = hs_all[wv];

  // ---- (2) h = relu(x @ Win + bin); sem = cosine sims ----
  f4v acc0 = {0.f,0.f,0.f,0.f}, acc1 = {0.f,0.f,0.f,0.f};
  f4v acc2 = {0.f,0.f,0.f,0.f}, acc3 = {0.f,0.f,0.f,0.f};
  const float* xrow = x + (size_t)(nb + mrow) * IN_DIM + q * 8;
  #pragma unroll 4
  for (int s = 0; s < 8; ++s) {
    float4 u0 = *(const float4*)(xrow + s * 32);
    float4 u1 = *(const float4*)(xrow + s * 32 + 4);
    float uu[8] = {u0.x, u0.y, u0.z, u0.w, u1.x, u1.y, u1.z, u1.w};
    s8v ah, al;
    split8(uu, ah, al);
    const u16* wp = wbT + s * 2048 + lane * 8;
    s8v b0 = *(const s8v*)(wp);
    s8v b1 = *(const s8v*)(wp + 512);
    s8v b2 = *(const s8v*)(wp + 1024);
    s8v b3 = *(const s8v*)(wp + 1536);
    acc0 = __builtin_amdgcn_mfma_f32_16x16x32_bf16(ah, b0, acc0, 0, 0, 0);
    acc0 = __builtin_amdgcn_mfma_f32_16x16x32_bf16(al, b0, acc0, 0, 0, 0);
    acc1 = __builtin_amdgcn_mfma_f32_16x16x32_bf16(ah, b1, acc1, 0, 0, 0);
    acc1 = __builtin_amdgcn_mfma_f32_16x16x32_bf16(al, b1, acc1, 0, 0, 0);
    acc2 = __builtin_amdgcn_mfma_f32_16x16x32_bf16(ah, b2, acc2, 0, 0, 0);
    acc2 = __builtin_amdgcn_mfma_f32_16x16x32_bf16(al, b2, acc2, 0, 0, 0);
    acc3 = __builtin_amdgcn_mfma_f32_16x16x32_bf16(ah, b3, acc3, 0, 0, 0);
    acc3 = __builtin_amdgcn_mfma_f32_16x16x32_bf16(al, b3, acc3, 0, 0, 0);
  }

  float bt[4], p0t[4], p1t[4];
  #pragma unroll
  for (int t = 0; t < 4; ++t) {
    bt[t]  = bin[t * 16 + mrow];
    p0t[t] = proto[t * 16 + mrow];
    p1t[t] = proto[64 + t * 16 + mrow];
  }
  float np0 = 0.f, np1 = 0.f;
  #pragma unroll
  for (int t = 0; t < 4; ++t) { np0 += p0t[t] * p0t[t]; np1 += p1t[t] * p1t[t]; }
  #pragma unroll
  for (int mm = 1; mm < 16; mm <<= 1) {
    np0 += __shfl_xor(np0, mm); np1 += __shfl_xor(np1, mm);
  }
  const float ip0 = 1.f / (sqrtf(np0) + 1e-12f);
  const float ip1 = 1.f / (sqrtf(np1) + 1e-12f);

  float hcol[4][4];
  #pragma unroll
  for (int r = 0; r < 4; ++r) {
    hcol[0][r] = fmaxf(acc0[r] + bt[0], 0.f);
    hcol[1][r] = fmaxf(acc1[r] + bt[1], 0.f);
    hcol[2][r] = fmaxf(acc2[r] + bt[2], 0.f);
    hcol[3][r] = fmaxf(acc3[r] + bt[3], 0.f);
  }
  #pragma unroll
  for (int r = 0; r < 4; ++r) {
    float r0 = 0.f, r1 = 0.f, r2 = 0.f;
    #pragma unroll
    for (int t = 0; t < 4; ++t) {
      float h = hcol[t][r];
      r0 += h * h; r1 += h * p0t[t]; r2 += h * p1t[t];
    }
    #pragma unroll
    for (int mm = 1; mm < 16; mm <<= 1) {
      r0 += __shfl_xor(r0, mm); r1 += __shfl_xor(r1, mm); r2 += __shfl_xor(r2, mm);
    }
    const int node = q * 4 + r;
    #pragma unroll
    for (int t = 0; t < 4; ++t)
      hs[node * HS_STRIDE + t * 16 + mrow] = hcol[t][r];
    if (!FULL) {
      float* row = ha + (size_t)(nb + node) * 68;
      #pragma unroll
      for (int t = 0; t < 4; ++t) row[t * 16 + mrow] = hcol[t][r];
    }
    if (mrow == 0) {
      float hi = 1.f / (sqrtf(r0) + 1e-12f);
      float s0 = r1 * hi * ip0, s1 = r2 * hi * ip1;
      hs[node * HS_STRIDE + 64] = s0;
      hs[node * HS_STRIDE + 65] = s1;
      if (!FULL) {
        float* row = ha + (size_t)(nb + node) * 68;
        row[64] = s0; row[65] = s1;
      }
    }
  }

  // ---- (3) A-fragments from LDS h-tile ----
  s8v ahs[3], als[3];
  #pragma unroll
  for (int s = 0; s < 3; ++s) {
    float uu[8];
    if (s < 2) {
      float4 u0 = *(const float4*)(hs + mrow * HS_STRIDE + s * 32 + q * 8);
      float4 u1 = *(const float4*)(hs + mrow * HS_STRIDE + s * 32 + q * 8 + 4);
      uu[0]=u0.x; uu[1]=u0.y; uu[2]=u0.z; uu[3]=u0.w;
      uu[4]=u1.x; uu[5]=u1.y; uu[6]=u1.z; uu[7]=u1.w;
    } else {
      #pragma unroll
      for (int j = 0; j < 8; ++j) uu[j] = 0.f;
      if (q == 0) {
        uu[0] = hs[mrow * HS_STRIDE + 64];
        uu[1] = hs[mrow * HS_STRIDE + 65];
      }
    }
    split8(uu, ahs[s], als[s]);
  }

  // ---- (4+5) merged: xl (and xr when FULL) per t; 6 loads in flight ----
  #pragma unroll 2
  for (int t = 0; t < 16; ++t) {
    f4v accl = {0.f, 0.f, 0.f, 0.f};
    f4v accr = {0.f, 0.f, 0.f, 0.f};
    #pragma unroll
    for (int s = 0; s < 3; ++s) {
      s8v bvl = *(const s8v*)(wlT + s * 8192 + t * 512 + lane * 8);
      accl = __builtin_amdgcn_mfma_f32_16x16x32_bf16(ahs[s], bvl, accl, 0, 0, 0);
      accl = __builtin_amdgcn_mfma_f32_16x16x32_bf16(als[s], bvl, accl, 0, 0, 0);
    }
    if (FULL) {
      #pragma unroll
      for (int s = 0; s < 3; ++s) {
        s8v bvr = *(const s8v*)(wrT + s * 8192 + t * 512 + lane * 8);
        accr = __builtin_amdgcn_mfma_f32_16x16x32_bf16(ahs[s], bvr, accr, 0, 0, 0);
        accr = __builtin_amdgcn_mfma_f32_16x16x32_bf16(als[s], bvr, accr, 0, 0, 0);
      }
    }
    float bcl = bl[t * 16 + mrow];
    #pragma unroll
    for (int r = 0; r < 4; ++r)
      xls[(size_t)(nb + q * 4 + r) * 256 + t * 16 + mrow] = f2h(accl[r] + bcl);
    if (FULL) {
      float bcr = br[t * 16 + mrow];
      #pragma unroll
      for (int r = 0; r < 4; ++r)
        xrs[(size_t)(nb + q * 4 + r) * 256 + t * 16 + mrow] = f2h(accr[r] + bcr);
    }
  }
}

// ---------------------------------------------------------------------------
// K_AGG (R19 + int4 index loads): packed-f16 edge math, 3-deep pipeline,
// 32-bit saddr gathers, DPP 16-lane reduction, split tail. Bucket CSR:
// kb = n*64 (256B-aligned), so each quad's 4 indices load as one int4.
// ---------------------------------------------------------------------------
template <int CTRL>
__device__ __forceinline__ float dppadd(float g) {
  return g + __int_as_float(__builtin_amdgcn_update_dpp(
      0, __float_as_int(g), CTRL, 0xF, 0xF, true));
}

__device__ __forceinline__ float red16_dpp(float g) {
  g = dppadd<0xB1>(g);   // quad_perm [1,0,3,2]
  g = dppadd<0x4E>(g);   // quad_perm [2,3,0,1]
  g = dppadd<0x124>(g);  // row_ror:4
  g = dppadd<0x128>(g);  // row_ror:8
  return g;
}

__device__ __forceinline__ float edge_h(uint2 rv, h2 xr01, h2 xr23,
                                        h2 av01, h2 av23,
                                        h2& x01, h2& x23) {
  x01 = __builtin_bit_cast(h2, rv.x);
  x23 = __builtin_bit_cast(h2, rv.y);
  h2 t01 = x01 + xr01, t23 = x23 + xr23;
  t01 = __builtin_elementwise_max(t01, t01 * (_Float16)0.2f);
  t23 = __builtin_elementwise_max(t23, t23 * (_Float16)0.2f);
  float g = __builtin_amdgcn_fdot2(t01, av01, 0.f, false);
  return __builtin_amdgcn_fdot2(t23, av23, g, false);
}

template <int INLINE_XR>
__global__ __launch_bounds__(256) void k_agg(
    const u16* __restrict__ xls, const u16* __restrict__ xrs,
    const float* __restrict__ ha, const float* __restrict__ Wr,
    const float* __restrict__ br,
    const int* __restrict__ esrc_b, const int* __restrict__ cnt,
    const float* __restrict__ att, const float* __restrict__ gbias,
    const float* __restrict__ wcls, const float* __restrict__ bcls,
    float* __restrict__ out)
{
  __shared__ u16 wr[INLINE_XR ? GAT_IN * 256 : 64];
  if (INLINE_XR) {
    for (int m = threadIdx.x; m < GAT_IN * 256; m += 256) wr[m] = f2bf(Wr[m]);
    __syncthreads();
  }
  const int lane = threadIdx.x & 63;
  const int n = __builtin_amdgcn_readfirstlane(blockIdx.x * 4 + (threadIdx.x >> 6));
  if (n >= N_NODES) return;

  float4 avr = *(const float4*)(att + lane * 4);
  const h2 av01 = {(_Float16)avr.x, (_Float16)avr.y};
  const h2 av23 = {(_Float16)avr.z, (_Float16)avr.w};

  h2 xr01, xr23;
  if (INLINE_XR) {
    float4 bv = *(const float4*)(br + lane * 4);
    float y0 = bv.x, y1 = bv.y, y2 = bv.z, y3 = bv.w;
    const float* hrow = ha + (size_t)n * 68;
    for (int i = 0; i < GAT_IN; ++i) {
      ushort4 wv = *(const ushort4*)&wr[i * 256 + lane * 4];
      float hv = hrow[i];
      y0 += hv * bf2f(wv.x); y1 += hv * bf2f(wv.y);
      y2 += hv * bf2f(wv.z); y3 += hv * bf2f(wv.w);
    }
    xr01 = (h2){(_Float16)y0, (_Float16)y1};
    xr23 = (h2){(_Float16)y2, (_Float16)y3};
  } else {
    uint2 qv = *(const uint2*)(xrs + (size_t)n * 256 + lane * 4);
    xr01 = __builtin_bit_cast(h2, qv.x);
    xr23 = __builtin_bit_cast(h2, qv.y);
  }

  const int kb = n << 6;   // bucket base (CAP = 64), 256B-aligned
  int dg = __builtin_amdgcn_readfirstlane(cnt[n]);
  if (dg < 0) dg = 0;
  if (dg > CAP) dg = CAP;
  const int ke = kb + dg;
  const int nq = dg >> 2;                  // full quads

  // 32-bit saddr-form gathers off a uniform base: off = (row<<9) + lane*8
  const char* __restrict__ xb = (const char*)xls;
  const u32 loff = (u32)lane * 8u;
  #define GROW(s) (*(const uint2*)(xb + ((((u32)(s)) << 9) + loff)))

  // ---- pipeline prologue: rows q0,q1 in flight, indices for q2 (int4) ----
  uint2 p0, p1, p2, p3;        // rows for quad q (current)
  uint2 n0, n1, n2, n3;        // rows for quad q+1
  int4 jq = {0, 0, 0, 0};      // indices for quad q+2
  if (nq > 0) {
    int4 ia = *(const int4*)(esrc_b + kb);
    p0 = GROW(ia.x); p1 = GROW(ia.y); p2 = GROW(ia.z); p3 = GROW(ia.w);
    if (nq > 1) {
      int4 ib = *(const int4*)(esrc_b + kb + 4);
      n0 = GROW(ib.x); n1 = GROW(ib.y); n2 = GROW(ib.z); n3 = GROW(ib.w);
      if (nq > 2) jq = *(const int4*)(esrc_b + kb + 8);
    }
  }

  float l_, c0, c1, c2, c3;
  {  // self-loop (computed while the quad-0/1 gathers fly)
    uint2 rv = GROW(n);
    h2 x01, x23;
    float g = edge_h(rv, xr01, xr23, av01, av23, x01, x23);
    g = red16_dpp(g);
    float a = __expf(fminf(g, 60.f));
    l_ = a;
    c0 = a * (float)x01[0]; c1 = a * (float)x01[1];
    c2 = a * (float)x23[0]; c3 = a * (float)x23[1];
  }

  for (int q = 0; q < nq; ++q) {
    uint2 r0 = p0, r1 = p1, r2 = p2, r3 = p3;
    p0 = n0; p1 = n1; p2 = n2; p3 = n3;
    if (q + 2 < nq) {                    // uniform branch (scalar nq, q)
      n0 = GROW(jq.x); n1 = GROW(jq.y); n2 = GROW(jq.z); n3 = GROW(jq.w);
      if (q + 3 < nq)
        jq = *(const int4*)(esrc_b + kb + (q + 3) * 4);
    }
    h2 xa01, xa23, xb01, xb23, xc01, xc23, xd01, xd23;
    float g0 = edge_h(r0, xr01, xr23, av01, av23, xa01, xa23);
    float g1 = edge_h(r1, xr01, xr23, av01, av23, xb01, xb23);
    float g2 = edge_h(r2, xr01, xr23, av01, av23, xc01, xc23);
    float g3 = edge_h(r3, xr01, xr23, av01, av23, xd01, xd23);
    g0 = red16_dpp(g0); g1 = red16_dpp(g1);
    g2 = red16_dpp(g2); g3 = red16_dpp(g3);
    float a0 = __expf(fminf(g0, 60.f));
    float a1 = __expf(fminf(g1, 60.f));
    float a2 = __expf(fminf(g2, 60.f));
    float a3 = __expf(fminf(g3, 60.f));
    l_ += (a0 + a1) + (a2 + a3);
    c0 += a0 * (float)xa01[0] + a1 * (float)xb01[0]
        + a2 * (float)xc01[0] + a3 * (float)xd01[0];
    c1 += a0 * (float)xa01[1] + a1 * (float)xb01[1]
        + a2 * (float)xc01[1] + a3 * (float)xd01[1];
    c2 += a0 * (float)xa23[0] + a1 * (float)xb23[0]
        + a2 * (float)xc23[0] + a3 * (float)xd23[0];
    c3 += a0 * (float)xa23[1] + a1 * (float)xb23[1]
        + a2 * (float)xc23[1] + a3 * (float)xd23[1];
  }

  // ---- tail: 0..3 remaining edges, unmasked single-edge path ----
  for (int i = kb + nq * 4; i < ke; ++i) {
    int s = esrc_b[i];
    uint2 rv = GROW(s);
    h2 x01, x23;
    float g = edge_h(rv, xr01, xr23, av01, av23, x01, x23);
    g = red16_dpp(g);
    float a = __expf(fminf(g, 60.f));
    l_ += a;
    c0 += a * (float)x01[0]; c1 += a * (float)x01[1];
    c2 += a * (float)x23[0]; c3 += a * (float)x23[1];
  }
  #undef GROW

  float inv = 1.f / (l_ + 1e-16f);
  float v0 = c0 * inv, v1 = c1 * inv, v2 = c2 * inv, v3 = c3 * inv;
  v0 += __shfl_xor(v0, 16); v0 += __shfl_xor(v0, 32);
  v1 += __shfl_xor(v1, 16); v1 += __shfl_xor(v1, 32);
  v2 += __shfl_xor(v2, 16); v2 += __shfl_xor(v2, 32);
  v3 += __shfl_xor(v3, 16); v3 += __shfl_xor(v3, 32);
  const int g4 = (lane & 15) * 4;
  const int h = lane >> 4;
  float4 gb = *(const float4*)(gbias + g4);
  v0 = fmaxf(0.25f * v0 + gb.x, 0.f);
  v1 = fmaxf(0.25f * v1 + gb.y, 0.f);
  v2 = fmaxf(0.25f * v2 + gb.z, 0.f);
  v3 = fmaxf(0.25f * v3 + gb.w, 0.f);
  float4 w0 = *(const float4*)(wcls + (g4 + 0) * 16 + h * 4);
  float4 w1 = *(const float4*)(wcls + (g4 + 1) * 16 + h * 4);
  float4 w2 = *(const float4*)(wcls + (g4 + 2) * 16 + h * 4);
  float4 w3 = *(const float4*)(wcls + (g4 + 3) * 16 + h * 4);
  float o0 = v0 * w0.x + v1 * w1.x + v2 * w2.x + v3 * w3.x;
  float o1 = v0 * w0.y + v1 * w1.y + v2 * w2.y + v3 * w3.y;
  float o2 = v0 * w0.z + v1 * w1.z + v2 * w2.z + v3 * w3.z;
  float o3 = v0 * w0.w + v1 * w1.w + v2 * w2.w + v3 * w3.w;
  #pragma unroll
  for (int mm = 1; mm < 16; mm <<= 1) {
    o0 += __shfl_xor(o0, mm); o1 += __shfl_xor(o1, mm);
    o2 += __shfl_xor(o2, mm); o3 += __shfl_xor(o3, mm);
  }
  if ((lane & 15) == 0) {
    float4 bcv = *(const float4*)(bcls + h * 4);
    float4 ov;
    ov.x = o0 + bcv.x; ov.y = o1 + bcv.y; ov.z = o2 + bcv.z; ov.w = o3 + bcv.w;
    *(float4*)(out + (size_t)n * 16 + h * 4) = ov;
  }
}

// ---------------------------------------------------------------------------
extern "C" void kernel_launch(void* const* d_in, const int* in_sizes, int n_in,
                              void* d_out, int out_size, void* d_ws, size_t ws_size,
                              hipStream_t stream)
{
  const float* x     = (const float*)d_in[0];
  const void*  ei    = d_in[1];
  const float* Win   = (const float*)d_in[2];
  const float* bin   = (const float*)d_in[3];
  const float* proto = (const float*)d_in[4];
  const float* Wl    = (const float*)d_in[5];
  const float* bl    = (const float*)d_in[6];
  const float* Wr    = (const float*)d_in[7];
  const float* br    = (const float*)d_in[8];
  const float* att   = (const float*)d_in[9];
  const float* gbias = (const float*)d_in[10];
  const float* wcls  = (const float*)d_in[11];
  const float* bcls  = (const float*)d_in[12];
  float* out = (float*)d_out;

  char* p = (char*)d_ws;
  size_t used = 0;
  auto carve = [&](size_t bytes) {
    char* q = p + used;
    used += (bytes + 255) & ~(size_t)255;
    return (void*)q;
  };
  int* flags  = (int*)carve(256);               // [0]=spare, [1]=isl
  int* cnt    = (int*)carve(N_NODES * 4);
  int* esrc_b = (int*)carve((size_t)N_NODES * CAP * 4);   // 12.8 MB buckets
  u16* wbT    = (u16*)carve(16384 * 2);
  u16* wlT    = (u16*)carve(24576 * 2);
  u16* wrT    = (u16*)carve(24576 * 2);
  u16* xls    = (u16*)carve((size_t)N_NODES * 256 * 2);
  // ha (13.6 MB, fallback only) and xrs (25.6 MB, full only) share a buffer:
  const size_t base = used;
  void* big = carve((size_t)N_NODES * 256 * 2);  // 25.6 MB
  float* ha = (float*)big;
  u16* xrs  = (u16*)big;
  const bool full = ws_size >= base + (size_t)N_NODES * 256 * 2;

  k_prep<<<196, 256, 0, stream>>>(Win, Wl, Wr, ei, wbT, wlT, wrT, cnt, flags);
  if (full)
    k_work<1><<<MEGA_BLOCKS + SCAT_BLOCKS, 256, 0, stream>>>(
        x, wbT, bin, proto, wlT, bl, wrT, br, ha, xls, xrs,
        ei, flags, cnt, esrc_b);
  else
    k_work<0><<<MEGA_BLOCKS + SCAT_BLOCKS, 256, 0, stream>>>(
        x, wbT, bin, proto, wlT, bl, wrT, br, ha, xls, xrs,
        ei, flags, cnt, esrc_b);
  if (full)
    k_agg<0><<<12500, 256, 0, stream>>>(xls, xrs, ha, Wr, br, esrc_b, cnt,
                                        att, gbias, wcls, bcls, out);
  else
    k_agg<1><<<12500, 256, 0, stream>>>(xls, xrs, ha, Wr, br, esrc_b, cnt,
                                        att, gbias, wcls, bcls, out);
}